// Round 1
// baseline (302.638 us; speedup 1.0000x reference)
//
#include <hip/hip_runtime.h>
#include <hip/hip_bf16.h>
#include <math.h>

typedef __attribute__((ext_vector_type(8))) short short8;
typedef __attribute__((ext_vector_type(4))) float f32x4;

#define NCH 64
#define CT 32

__device__ __forceinline__ unsigned short f2bf(float f) {
  unsigned u = __builtin_bit_cast(unsigned, f);
  u += 0x7fffu + ((u >> 16) & 1u);
  return (unsigned short)(u >> 16);
}
__device__ __forceinline__ float sigm(float x) { return 1.f / (1.f + __expf(-x)); }

__device__ __forceinline__ void stage16(const void* g, void* l) {
  __builtin_amdgcn_global_load_lds(
      (const __attribute__((address_space(1))) unsigned int*)(unsigned long long)g,
      (__attribute__((address_space(3))) unsigned int*)(unsigned)(unsigned long long)l,
      16, 0, 0);
}

// ---------------- prep ----------------
// xb: 2050x1024 bf16, rows 0,1 zero, row r>=2 = x[r-2]
__global__ void prep_xpad(const float* __restrict__ x, unsigned short* __restrict__ xb) {
  int idx = (blockIdx.x * 256 + threadIdx.x) * 4;
  if (idx >= 2050 * 1024) return;
  int row = idx >> 10, col = idx & 1023;
  float v0 = 0.f, v1 = 0.f, v2 = 0.f, v3 = 0.f;
  if (row >= 2) {
    const float4 v = *(const float4*)(x + (size_t)(row - 2) * 1024 + col);
    v0 = v.x; v1 = v.y; v2 = v.z; v3 = v.w;
  }
  unsigned long long pk = (unsigned long long)f2bf(v0)
      | ((unsigned long long)f2bf(v1) << 16)
      | ((unsigned long long)f2bf(v2) << 32)
      | ((unsigned long long)f2bf(v3) << 48);
  *(unsigned long long*)(xb + idx) = pk;
}

// cwt[d][k*1024+i] = bf16(conv_w[d][i][k])
__global__ void prep_convw(const float* __restrict__ cw, unsigned short* __restrict__ cwt) {
  int idx = blockIdx.x * 256 + threadIdx.x;  // (d,i) over 2048*1024
  int d = idx >> 10, i = idx & 1023;
  const float* p = cw + (size_t)d * 3072 + (size_t)i * 3;
  unsigned short* q = cwt + (size_t)d * 3072 + i;
  q[0] = f2bf(p[0]);
  q[1024] = f2bf(p[1]);
  q[2048] = f2bf(p[2]);
}

// Wt[n][i] = bf16(W[i][col_off + n]); W ld = src_ld, Wt ld = rowsI
__global__ void transpose_bf16(const float* __restrict__ W, int src_ld, int col_off,
                               unsigned short* __restrict__ Wt, int rowsI) {
  __shared__ float tile[32][33];
  int n0 = blockIdx.x * 32, i0 = blockIdx.y * 32;
  int tx = threadIdx.x & 31, ty = threadIdx.x >> 5;  // 32 x 8
#pragma unroll
  for (int rr = 0; rr < 32; rr += 8)
    tile[ty + rr][tx] = W[(size_t)(i0 + ty + rr) * src_ld + col_off + n0 + tx];
  __syncthreads();
#pragma unroll
  for (int rr = 0; rr < 32; rr += 8)
    Wt[(size_t)(n0 + ty + rr) * rowsI + i0 + tx] = f2bf(tile[tx][ty + rr]);
}

// ---------------- GEMM: C[M,N] = A[M,K] * Bt[N,K]^T (+bias, epilogue) ----------------
// MODE 0: outf=val, outb=bf16(val)   MODE 1: outf=val   MODE 2: outf = mulsrc * sigmoid(val)
template <int MODE>
__global__ __launch_bounds__(256, 2) void gemm128(
    const unsigned short* __restrict__ A, int lda,
    const unsigned short* __restrict__ Bt, int ldb, int K,
    const float* __restrict__ bias,
    float* __restrict__ outf, int ldo,
    unsigned short* __restrict__ outb,
    const float* __restrict__ mulsrc) {
  __shared__ unsigned short As[128 * 64];
  __shared__ unsigned short Bs[128 * 64];
  const int tid = threadIdx.x;
  const int lane = tid & 63;
  const int w = tid >> 6;
  const int wr = w >> 1, wc = w & 1;
  const int bm = blockIdx.x, bn = blockIdx.y;

  f32x4 acc[4][4];
#pragma unroll
  for (int m = 0; m < 4; ++m)
#pragma unroll
    for (int n = 0; n < 4; ++n)
#pragma unroll
      for (int j = 0; j < 4; ++j) acc[m][n][j] = 0.f;

  const int crow = lane >> 3;
  const int ccol = (lane & 7) * 8;
  const int r = lane & 15;
  const int g8 = (lane >> 4) * 8;
  const int nk = K >> 6;

  for (int kt = 0; kt < nk; ++kt) {
    const int k0 = kt * 64;
#pragma unroll
    for (int c4 = 0; c4 < 4; ++c4) {
      const int c = w * 4 + c4;
      stage16(A + (size_t)(bm * 128 + c * 8 + crow) * lda + k0 + ccol, As + c * 512);
      stage16(Bt + (size_t)(bn * 128 + c * 8 + crow) * ldb + k0 + ccol, Bs + c * 512);
    }
    __syncthreads();
#pragma unroll
    for (int kk = 0; kk < 64; kk += 32) {
      short8 af[4], bfr[4];
#pragma unroll
      for (int m = 0; m < 4; ++m)
        af[m] = *(const short8*)&As[(wr * 64 + m * 16 + r) * 64 + kk + g8];
#pragma unroll
      for (int n = 0; n < 4; ++n)
        bfr[n] = *(const short8*)&Bs[(wc * 64 + n * 16 + r) * 64 + kk + g8];
#pragma unroll
      for (int m = 0; m < 4; ++m)
#pragma unroll
        for (int n = 0; n < 4; ++n)
          acc[m][n] = __builtin_amdgcn_mfma_f32_16x16x32_bf16(af[m], bfr[n], acc[m][n], 0, 0, 0);
    }
    __syncthreads();
  }

  const int cc = lane & 15;
  const int cr = (lane >> 4) * 4;
#pragma unroll
  for (int m = 0; m < 4; ++m) {
#pragma unroll
    for (int n = 0; n < 4; ++n) {
      const int col = bn * 128 + wc * 64 + n * 16 + cc;
      const float bv = bias[col];
#pragma unroll
      for (int j = 0; j < 4; ++j) {
        const int row = bm * 128 + wr * 64 + m * 16 + cr + j;
        const size_t o = (size_t)row * ldo + col;
        float v = acc[m][n][j] + bv;
        if (MODE == 0) { outf[o] = v; outb[o] = f2bf(v); }
        else if (MODE == 1) { outf[o] = v; }
        else { outf[o] = mulsrc[o] * sigm(v); }
      }
    }
  }
}

// ---------------- bc + dt ----------------
__global__ __launch_bounds__(256) void bcdt(const float* __restrict__ xc,
                                            const float* __restrict__ xpw,
                                            const float* __restrict__ xpb,
                                            float* __restrict__ Bc, float* __restrict__ Cc,
                                            float* __restrict__ dt) {
  int s = blockIdx.x;
  __shared__ float row[2048];
  __shared__ float red[256];
  __shared__ float pj[8][32];
  const float* xr = xc + (size_t)s * 2048;
  float lsum = 0.f;
  for (int i = threadIdx.x; i < 2048; i += 256) {
    float v = xr[i];
    row[i] = v;
    lsum += v;
  }
  red[threadIdx.x] = lsum;
  __syncthreads();
  for (int off = 128; off > 0; off >>= 1) {
    if (threadIdx.x < off) red[threadIdx.x] += red[threadIdx.x + off];
    __syncthreads();
  }
  if (threadIdx.x == 0) dt[s] = sigm(red[0] * (1.f / 2048.f)) + 0.001f;

  int j = threadIdx.x & 31, seg = threadIdx.x >> 5;
  float acc = 0.f;
  int kbase = seg * 256;
  for (int k = 0; k < 256; ++k) acc += row[kbase + k] * xpw[(size_t)(kbase + k) * 32 + j];
  pj[seg][j] = acc;
  __syncthreads();
  if (threadIdx.x < 32) {
    float v = xpb[threadIdx.x];
#pragma unroll
    for (int rr = 0; rr < 8; ++rr) v += pj[rr][threadIdx.x];
    if (threadIdx.x < 16) Bc[(size_t)s * 16 + threadIdx.x] = v;
    else Cc[(size_t)s * 16 + threadIdx.x - 16] = v;
  }
}

// ---------------- scan ----------------
__global__ __launch_bounds__(256) void scan_local(const float* __restrict__ A_log,
                                                  const float* __restrict__ dt,
                                                  const float* __restrict__ Bc,
                                                  const float* __restrict__ u,
                                                  float* __restrict__ Hloc) {
  int d = blockIdx.x * 256 + threadIdx.x;
  int c = blockIdx.y;
  __shared__ float sB[CT][16];
  __shared__ float sdt[CT];
  for (int i = threadIdx.x; i < CT * 16; i += 256) sB[i >> 4][i & 15] = Bc[(size_t)c * CT * 16 + i];
  if (threadIdx.x < CT) sdt[threadIdx.x] = dt[c * CT + threadIdx.x];
  __syncthreads();
  float cA[16], h[16];
#pragma unroll
  for (int n = 0; n < 16; ++n) {
    float al = A_log[(size_t)d * 16 + n];
    cA[n] = log1pf(__expf(al)) * 1.4426950408889634f;
    h[n] = 0.f;
  }
  for (int t = 0; t < CT; ++t) {
    float dtv = sdt[t];
    float du = dtv * u[(size_t)(c * CT + t) * 2048 + d];
#pragma unroll
    for (int n = 0; n < 16; ++n) {
      float ab = exp2f(cA[n] * dtv);
      h[n] = ab * (h[n] + sB[t][n] * du);
    }
  }
#pragma unroll
  for (int n = 0; n < 16; ++n) Hloc[(size_t)c * 32768 + (size_t)d * 16 + n] = h[n];
}

__global__ __launch_bounds__(256) void scan_carry(const float* __restrict__ A_log,
                                                  const float* __restrict__ dt,
                                                  const float* __restrict__ Hloc,
                                                  float* __restrict__ hstart) {
  int g = blockIdx.x * 256 + threadIdx.x;  // 32768 = d*16+n
  __shared__ float sS[NCH];
  if (threadIdx.x < NCH) {
    float s = 0.f;
    for (int t = 0; t < CT; ++t) s += dt[threadIdx.x * CT + t];
    sS[threadIdx.x] = s;
  }
  __syncthreads();
  float al = A_log[g];
  float cA = log1pf(__expf(al)) * 1.4426950408889634f;
  float h = 0.f;
  for (int c = 0; c < NCH; ++c) {
    hstart[(size_t)c * 32768 + g] = h;
    float P = exp2f(cA * sS[c]);
    h = P * h + Hloc[(size_t)c * 32768 + g];
  }
}

__global__ __launch_bounds__(256) void scan_final(const float* __restrict__ A_log,
                                                  const float* __restrict__ dt,
                                                  const float* __restrict__ Bc,
                                                  const float* __restrict__ Cc,
                                                  const float* __restrict__ u,
                                                  const float* __restrict__ zpre,
                                                  const float* __restrict__ Dp,
                                                  const float* __restrict__ hstart,
                                                  unsigned short* __restrict__ ob) {
  int d = blockIdx.x * 256 + threadIdx.x;
  int c = blockIdx.y;
  __shared__ float sB[CT][16], sC[CT][16], sdt[CT];
  for (int i = threadIdx.x; i < CT * 16; i += 256) {
    sB[i >> 4][i & 15] = Bc[(size_t)c * CT * 16 + i];
    sC[i >> 4][i & 15] = Cc[(size_t)c * CT * 16 + i];
  }
  if (threadIdx.x < CT) sdt[threadIdx.x] = dt[c * CT + threadIdx.x];
  __syncthreads();
  float cA[16], h[16];
#pragma unroll
  for (int n = 0; n < 16; ++n) {
    float al = A_log[(size_t)d * 16 + n];
    cA[n] = log1pf(__expf(al)) * 1.4426950408889634f;
    h[n] = hstart[(size_t)c * 32768 + (size_t)d * 16 + n];
  }
  float Dv = Dp[d];
  for (int t = 0; t < CT; ++t) {
    float dtv = sdt[t];
    size_t idx = (size_t)(c * CT + t) * 2048 + d;
    float uv = u[idx];
    float du = dtv * uv;
    float y = Dv * uv;
#pragma unroll
    for (int n = 0; n < 16; ++n) {
      float ab = exp2f(cA[n] * dtv);
      h[n] = ab * (h[n] + sB[t][n] * du);
      y += h[n] * sC[t][n];
    }
    float o = y * sigm(zpre[idx]);
    ob[idx] = f2bf(o);
  }
}

// ---------------- launch ----------------
extern "C" void kernel_launch(void* const* d_in, const int* in_sizes, int n_in,
                              void* d_out, int out_size, void* d_ws, size_t ws_size,
                              hipStream_t stream) {
  (void)in_sizes; (void)n_in; (void)out_size; (void)ws_size;
  const float* x = (const float*)d_in[0];
  const float* in_proj_w = (const float*)d_in[1];
  const float* in_proj_b = (const float*)d_in[2];
  const float* conv_w = (const float*)d_in[3];
  const float* conv_b = (const float*)d_in[4];
  const float* A_log = (const float*)d_in[5];
  const float* Dp = (const float*)d_in[6];
  const float* x_proj_w = (const float*)d_in[7];
  const float* x_proj_b = (const float*)d_in[8];
  const float* gate_w = (const float*)d_in[9];
  const float* gate_b = (const float*)d_in[10];
  const float* o_proj_w = (const float*)d_in[11];
  const float* o_proj_b = (const float*)d_in[12];

  char* ws = (char*)d_ws;
  size_t off = 0;
  unsigned short* xb = (unsigned short*)(ws + off); off += (size_t)2050 * 1024 * 2;
  off = (off + 255) & ~(size_t)255;
  unsigned short* cwt = (unsigned short*)(ws + off); off += (size_t)2048 * 3072 * 2;
  unsigned short* wzt = (unsigned short*)(ws + off); off += (size_t)2048 * 1024 * 2;
  unsigned short* gwt = (unsigned short*)(ws + off); off += (size_t)2048 * 2048 * 2;
  unsigned short* owt = (unsigned short*)(ws + off); off += (size_t)1024 * 2048 * 2;
  float* xc = (float*)(ws + off); off += (size_t)2048 * 2048 * 4;
  unsigned short* xcb = (unsigned short*)(ws + off); off += (size_t)2048 * 2048 * 2;
  float* zpre = (float*)(ws + off); off += (size_t)2048 * 2048 * 4;
  float* uu = (float*)(ws + off); off += (size_t)2048 * 2048 * 4;
  float* dtv = (float*)(ws + off); off += (size_t)2048 * 4;
  float* Bc = (float*)(ws + off); off += (size_t)2048 * 16 * 4;
  float* Cc = (float*)(ws + off); off += (size_t)2048 * 16 * 4;
  float* Hloc = (float*)(ws + off); off += (size_t)NCH * 2048 * 16 * 4;
  float* hstart = (float*)(ws + off); off += (size_t)NCH * 2048 * 16 * 4;
  unsigned short* ob = (unsigned short*)(ws + off); off += (size_t)2048 * 2048 * 2;

  prep_xpad<<<2050, 256, 0, stream>>>(x, xb);
  prep_convw<<<8192, 256, 0, stream>>>(conv_w, cwt);
  transpose_bf16<<<dim3(64, 32), 256, 0, stream>>>(in_proj_w, 4096, 2048, wzt, 1024);
  transpose_bf16<<<dim3(64, 64), 256, 0, stream>>>(gate_w, 2048, 0, gwt, 2048);
  transpose_bf16<<<dim3(32, 64), 256, 0, stream>>>(o_proj_w, 1024, 0, owt, 2048);

  // conv as GEMM: A = xb (lda=1024, K=3072 overlapping-row trick), Bt = cwt
  gemm128<0><<<dim3(16, 16), 256, 0, stream>>>(xb, 1024, cwt, 3072, 3072, conv_b, xc, 2048, xcb, nullptr);
  // z projection: A = x rows (xb shifted by 2 pad rows), Bt = wzt
  gemm128<1><<<dim3(16, 16), 256, 0, stream>>>(xb + 2 * 1024, 1024, wzt, 1024, 1024, in_proj_b + 2048, zpre, 2048, nullptr, nullptr);
  bcdt<<<2048, 256, 0, stream>>>(xc, x_proj_w, x_proj_b, Bc, Cc, dtv);
  // gate: u = xc * sigmoid(xcb @ gwt^T + gate_b)
  gemm128<2><<<dim3(16, 16), 256, 0, stream>>>(xcb, 2048, gwt, 2048, 2048, gate_b, uu, 2048, nullptr, xc);

  scan_local<<<dim3(8, NCH), 256, 0, stream>>>(A_log, dtv, Bc, uu, Hloc);
  scan_carry<<<128, 256, 0, stream>>>(A_log, dtv, Hloc, hstart);
  scan_final<<<dim3(8, NCH), 256, 0, stream>>>(A_log, dtv, Bc, Cc, uu, zpre, Dp, hstart, ob);

  // output projection
  gemm128<1><<<dim3(16, 8), 256, 0, stream>>>(ob, 2048, owt, 2048, 2048, o_proj_b, (float*)d_out, 1024, nullptr, nullptr);
}

// Round 2
// 223.856 us; speedup vs baseline: 1.3519x; 1.3519x over previous
//
#include <hip/hip_runtime.h>
#include <hip/hip_bf16.h>
#include <math.h>

typedef __attribute__((ext_vector_type(8))) short short8;
typedef __attribute__((ext_vector_type(4))) float f32x4;

#define NCH 64
#define CT 32

__device__ __forceinline__ unsigned short f2bf(float f) {
  unsigned u = __builtin_bit_cast(unsigned, f);
  u += 0x7fffu + ((u >> 16) & 1u);
  return (unsigned short)(u >> 16);
}
__device__ __forceinline__ float sigm(float x) { return 1.f / (1.f + __expf(-x)); }

__device__ __forceinline__ void stage16(const void* g, void* l) {
  __builtin_amdgcn_global_load_lds(
      (const __attribute__((address_space(1))) unsigned int*)(unsigned long long)g,
      (__attribute__((address_space(3))) unsigned int*)(unsigned)(unsigned long long)l,
      16, 0, 0);
}

// ---------------- prep ----------------
__global__ void prep_xpad(const float* __restrict__ x, unsigned short* __restrict__ xb) {
  int idx = (blockIdx.x * 256 + threadIdx.x) * 4;
  if (idx >= 2050 * 1024) return;
  int row = idx >> 10, col = idx & 1023;
  float v0 = 0.f, v1 = 0.f, v2 = 0.f, v3 = 0.f;
  if (row >= 2) {
    const float4 v = *(const float4*)(x + (size_t)(row - 2) * 1024 + col);
    v0 = v.x; v1 = v.y; v2 = v.z; v3 = v.w;
  }
  unsigned long long pk = (unsigned long long)f2bf(v0)
      | ((unsigned long long)f2bf(v1) << 16)
      | ((unsigned long long)f2bf(v2) << 32)
      | ((unsigned long long)f2bf(v3) << 48);
  *(unsigned long long*)(xb + idx) = pk;
}

__global__ void prep_convw(const float* __restrict__ cw, unsigned short* __restrict__ cwt) {
  int idx = blockIdx.x * 256 + threadIdx.x;
  int d = idx >> 10, i = idx & 1023;
  const float* p = cw + (size_t)d * 3072 + (size_t)i * 3;
  unsigned short* q = cwt + (size_t)d * 3072 + i;
  q[0] = f2bf(p[0]);
  q[1024] = f2bf(p[1]);
  q[2048] = f2bf(p[2]);
}

__global__ void transpose_bf16(const float* __restrict__ W, int src_ld, int col_off,
                               unsigned short* __restrict__ Wt, int rowsI) {
  __shared__ float tile[32][33];
  int n0 = blockIdx.x * 32, i0 = blockIdx.y * 32;
  int tx = threadIdx.x & 31, ty = threadIdx.x >> 5;
#pragma unroll
  for (int rr = 0; rr < 32; rr += 8)
    tile[ty + rr][tx] = W[(size_t)(i0 + ty + rr) * src_ld + col_off + n0 + tx];
  __syncthreads();
#pragma unroll
  for (int rr = 0; rr < 32; rr += 8)
    Wt[(size_t)(n0 + ty + rr) * rowsI + i0 + tx] = f2bf(tile[tx][ty + rr]);
}

// ---------------- GEMM: C[M,N] = A[M,K] * Bt[N,K]^T (+bias, epilogue) ----------------
// Swizzled LDS (both-sides XOR of 16B slot with row&7), double-buffered prefetch.
// MODE 0: outf=val, outb=bf16(val)   MODE 1: outf=val   MODE 2: outf = mulsrc * sigmoid(val)
template <int MODE, int BM, int BN>
__global__ __launch_bounds__(256, 2) void gemm_t(
    const unsigned short* __restrict__ A, int lda,
    const unsigned short* __restrict__ Bt, int ldb, int K,
    const float* __restrict__ bias,
    float* __restrict__ outf, int ldo,
    unsigned short* __restrict__ outb,
    const float* __restrict__ mulsrc) {
  constexpr int MR = BM / 32;  // A frags per wave (wave tile BM/2 rows)
  constexpr int NR = BN / 32;
  constexpr int IA = BM / 32;  // A stage instrs per wave (1KB each)
  constexpr int IB = BN / 32;
  __shared__ unsigned short As[2][BM * 64];
  __shared__ unsigned short Bs[2][BN * 64];

  const int tid = threadIdx.x;
  const int lane = tid & 63;
  const int w = tid >> 6;
  const int wr = w >> 1, wc = w & 1;
  const int bm = blockIdx.x, bn = blockIdx.y;

  f32x4 acc[MR][NR];
#pragma unroll
  for (int m = 0; m < MR; ++m)
#pragma unroll
    for (int n = 0; n < NR; ++n)
#pragma unroll
      for (int j = 0; j < 4; ++j) acc[m][n][j] = 0.f;

  // staging source: row-within-8 = lane>>3, swizzled slot = (lane&7) ^ (lane>>3)
  const int srow = lane >> 3;
  const int sslot = (lane & 7) ^ srow;
  const unsigned short* Ab = A + (size_t)(bm * BM + srow) * lda + sslot * 8;
  const unsigned short* Bb = Bt + (size_t)(bn * BN + srow) * ldb + sslot * 8;

  const int r = lane & 15;
  const int g = lane >> 4;  // 0..3
  const int nk = K >> 6;

  auto stage = [&](int buf, int k0) {
#pragma unroll
    for (int i = 0; i < IA; ++i) {
      const int cb = w * IA + i;
      stage16(Ab + (size_t)(cb * 8) * lda + k0, &As[buf][cb * 512]);
    }
#pragma unroll
    for (int i = 0; i < IB; ++i) {
      const int cb = w * IB + i;
      stage16(Bb + (size_t)(cb * 8) * ldb + k0, &Bs[buf][cb * 512]);
    }
  };

  auto compute = [&](int buf) {
#pragma unroll
    for (int kk = 0; kk < 64; kk += 32) {
      const int sb = (kk >> 3) + g;  // 16B-slot index 0..7
      short8 af[MR], bfr[NR];
#pragma unroll
      for (int m = 0; m < MR; ++m) {
        const int R = wr * (BM / 2) + m * 16 + r;
        af[m] = *(const short8*)&As[buf][R * 64 + ((sb ^ (R & 7)) << 3)];
      }
#pragma unroll
      for (int n = 0; n < NR; ++n) {
        const int R = wc * (BN / 2) + n * 16 + r;
        bfr[n] = *(const short8*)&Bs[buf][R * 64 + ((sb ^ (R & 7)) << 3)];
      }
#pragma unroll
      for (int m = 0; m < MR; ++m)
#pragma unroll
        for (int n = 0; n < NR; ++n)
          acc[m][n] = __builtin_amdgcn_mfma_f32_16x16x32_bf16(af[m], bfr[n], acc[m][n], 0, 0, 0);
    }
  };

  // prologue
  stage(0, 0);
  __syncthreads();  // compiler emits vmcnt(0) drain before barrier
  int cur = 0;
  for (int kt = 0; kt < nk; ++kt) {
    if (kt + 1 < nk) stage(cur ^ 1, (kt + 1) * 64);  // prefetch overlaps compute
    compute(cur);
    __syncthreads();  // drains prefetch vmcnt + protects buffer reuse
    cur ^= 1;
  }

  const int cc = lane & 15;
  const int cr = g * 4;
#pragma unroll
  for (int m = 0; m < MR; ++m) {
#pragma unroll
    for (int n = 0; n < NR; ++n) {
      const int col = bn * BN + wc * (BN / 2) + n * 16 + cc;
      const float bv = bias[col];
#pragma unroll
      for (int j = 0; j < 4; ++j) {
        const int row = bm * BM + wr * (BM / 2) + m * 16 + cr + j;
        const size_t o = (size_t)row * ldo + col;
        float v = acc[m][n][j] + bv;
        if (MODE == 0) { outf[o] = v; outb[o] = f2bf(v); }
        else if (MODE == 1) { outf[o] = v; }
        else { outf[o] = mulsrc[o] * sigm(v); }
      }
    }
  }
}

// ---------------- bc + dt ----------------
__global__ __launch_bounds__(256) void bcdt(const float* __restrict__ xc,
                                            const float* __restrict__ xpw,
                                            const float* __restrict__ xpb,
                                            float* __restrict__ Bc, float* __restrict__ Cc,
                                            float* __restrict__ dt) {
  int s = blockIdx.x;
  __shared__ float row[2048];
  __shared__ float red[256];
  __shared__ float pj[8][32];
  const float* xr = xc + (size_t)s * 2048;
  float lsum = 0.f;
  for (int i = threadIdx.x; i < 2048; i += 256) {
    float v = xr[i];
    row[i] = v;
    lsum += v;
  }
  red[threadIdx.x] = lsum;
  __syncthreads();
  for (int off = 128; off > 0; off >>= 1) {
    if (threadIdx.x < off) red[threadIdx.x] += red[threadIdx.x + off];
    __syncthreads();
  }
  if (threadIdx.x == 0) dt[s] = sigm(red[0] * (1.f / 2048.f)) + 0.001f;

  int j = threadIdx.x & 31, seg = threadIdx.x >> 5;
  float acc = 0.f;
  int kbase = seg * 256;
  for (int k = 0; k < 256; ++k) acc += row[kbase + k] * xpw[(size_t)(kbase + k) * 32 + j];
  pj[seg][j] = acc;
  __syncthreads();
  if (threadIdx.x < 32) {
    float v = xpb[threadIdx.x];
#pragma unroll
    for (int rr = 0; rr < 8; ++rr) v += pj[rr][threadIdx.x];
    if (threadIdx.x < 16) Bc[(size_t)s * 16 + threadIdx.x] = v;
    else Cc[(size_t)s * 16 + threadIdx.x - 16] = v;
  }
}

// ---------------- scan ----------------
__global__ __launch_bounds__(256) void scan_local(const float* __restrict__ A_log,
                                                  const float* __restrict__ dt,
                                                  const float* __restrict__ Bc,
                                                  const float* __restrict__ u,
                                                  float* __restrict__ Hloc) {
  int d = blockIdx.x * 256 + threadIdx.x;
  int c = blockIdx.y;
  __shared__ float sB[CT][16];
  __shared__ float sdt[CT];
  for (int i = threadIdx.x; i < CT * 16; i += 256) sB[i >> 4][i & 15] = Bc[(size_t)c * CT * 16 + i];
  if (threadIdx.x < CT) sdt[threadIdx.x] = dt[c * CT + threadIdx.x];
  __syncthreads();
  float cA[16], h[16];
#pragma unroll
  for (int n = 0; n < 16; ++n) {
    float al = A_log[(size_t)d * 16 + n];
    cA[n] = log1pf(__expf(al)) * 1.4426950408889634f;
    h[n] = 0.f;
  }
  for (int t = 0; t < CT; ++t) {
    float dtv = sdt[t];
    float du = dtv * u[(size_t)(c * CT + t) * 2048 + d];
#pragma unroll
    for (int n = 0; n < 16; ++n) {
      float ab = exp2f(cA[n] * dtv);
      h[n] = ab * (h[n] + sB[t][n] * du);
    }
  }
#pragma unroll
  for (int n = 0; n < 16; ++n) Hloc[(size_t)c * 32768 + (size_t)d * 16 + n] = h[n];
}

__global__ __launch_bounds__(256) void scan_carry(const float* __restrict__ A_log,
                                                  const float* __restrict__ dt,
                                                  const float* __restrict__ Hloc,
                                                  float* __restrict__ hstart) {
  int g = blockIdx.x * 256 + threadIdx.x;
  __shared__ float sS[NCH];
  if (threadIdx.x < NCH) {
    float s = 0.f;
    for (int t = 0; t < CT; ++t) s += dt[threadIdx.x * CT + t];
    sS[threadIdx.x] = s;
  }
  __syncthreads();
  float al = A_log[g];
  float cA = log1pf(__expf(al)) * 1.4426950408889634f;
  float h = 0.f;
  for (int c = 0; c < NCH; ++c) {
    hstart[(size_t)c * 32768 + g] = h;
    float P = exp2f(cA * sS[c]);
    h = P * h + Hloc[(size_t)c * 32768 + g];
  }
}

__global__ __launch_bounds__(256) void scan_final(const float* __restrict__ A_log,
                                                  const float* __restrict__ dt,
                                                  const float* __restrict__ Bc,
                                                  const float* __restrict__ Cc,
                                                  const float* __restrict__ u,
                                                  const float* __restrict__ zpre,
                                                  const float* __restrict__ Dp,
                                                  const float* __restrict__ hstart,
                                                  unsigned short* __restrict__ ob) {
  int d = blockIdx.x * 256 + threadIdx.x;
  int c = blockIdx.y;
  __shared__ float sB[CT][16], sC[CT][16], sdt[CT];
  for (int i = threadIdx.x; i < CT * 16; i += 256) {
    sB[i >> 4][i & 15] = Bc[(size_t)c * CT * 16 + i];
    sC[i >> 4][i & 15] = Cc[(size_t)c * CT * 16 + i];
  }
  if (threadIdx.x < CT) sdt[threadIdx.x] = dt[c * CT + threadIdx.x];
  __syncthreads();
  float cA[16], h[16];
#pragma unroll
  for (int n = 0; n < 16; ++n) {
    float al = A_log[(size_t)d * 16 + n];
    cA[n] = log1pf(__expf(al)) * 1.4426950408889634f;
    h[n] = hstart[(size_t)c * 32768 + (size_t)d * 16 + n];
  }
  float Dv = Dp[d];
  for (int t = 0; t < CT; ++t) {
    float dtv = sdt[t];
    size_t idx = (size_t)(c * CT + t) * 2048 + d;
    float uv = u[idx];
    float du = dtv * uv;
    float y = Dv * uv;
#pragma unroll
    for (int n = 0; n < 16; ++n) {
      float ab = exp2f(cA[n] * dtv);
      h[n] = ab * (h[n] + sB[t][n] * du);
      y += h[n] * sC[t][n];
    }
    float o = y * sigm(zpre[idx]);
    ob[idx] = f2bf(o);
  }
}

// ---------------- launch ----------------
extern "C" void kernel_launch(void* const* d_in, const int* in_sizes, int n_in,
                              void* d_out, int out_size, void* d_ws, size_t ws_size,
                              hipStream_t stream) {
  (void)in_sizes; (void)n_in; (void)out_size; (void)ws_size;
  const float* x = (const float*)d_in[0];
  const float* in_proj_w = (const float*)d_in[1];
  const float* in_proj_b = (const float*)d_in[2];
  const float* conv_w = (const float*)d_in[3];
  const float* conv_b = (const float*)d_in[4];
  const float* A_log = (const float*)d_in[5];
  const float* Dp = (const float*)d_in[6];
  const float* x_proj_w = (const float*)d_in[7];
  const float* x_proj_b = (const float*)d_in[8];
  const float* gate_w = (const float*)d_in[9];
  const float* gate_b = (const float*)d_in[10];
  const float* o_proj_w = (const float*)d_in[11];
  const float* o_proj_b = (const float*)d_in[12];

  char* ws = (char*)d_ws;
  size_t off = 0;
  unsigned short* xb = (unsigned short*)(ws + off); off += (size_t)2050 * 1024 * 2;
  off = (off + 255) & ~(size_t)255;
  unsigned short* cwt = (unsigned short*)(ws + off); off += (size_t)2048 * 3072 * 2;
  unsigned short* wzt = (unsigned short*)(ws + off); off += (size_t)2048 * 1024 * 2;
  unsigned short* gwt = (unsigned short*)(ws + off); off += (size_t)2048 * 2048 * 2;
  unsigned short* owt = (unsigned short*)(ws + off); off += (size_t)1024 * 2048 * 2;
  float* xc = (float*)(ws + off); off += (size_t)2048 * 2048 * 4;
  unsigned short* xcb = (unsigned short*)(ws + off); off += (size_t)2048 * 2048 * 2;
  float* zpre = (float*)(ws + off); off += (size_t)2048 * 2048 * 4;
  float* uu = (float*)(ws + off); off += (size_t)2048 * 2048 * 4;
  float* dtv = (float*)(ws + off); off += (size_t)2048 * 4;
  float* Bc = (float*)(ws + off); off += (size_t)2048 * 16 * 4;
  float* Cc = (float*)(ws + off); off += (size_t)2048 * 16 * 4;
  float* Hloc = (float*)(ws + off); off += (size_t)NCH * 2048 * 16 * 4;
  float* hstart = (float*)(ws + off); off += (size_t)NCH * 2048 * 16 * 4;
  unsigned short* ob = (unsigned short*)(ws + off); off += (size_t)2048 * 2048 * 2;

  prep_xpad<<<2050, 256, 0, stream>>>(x, xb);
  prep_convw<<<8192, 256, 0, stream>>>(conv_w, cwt);
  transpose_bf16<<<dim3(64, 32), 256, 0, stream>>>(in_proj_w, 4096, 2048, wzt, 1024);
  transpose_bf16<<<dim3(64, 64), 256, 0, stream>>>(gate_w, 2048, 0, gwt, 2048);
  transpose_bf16<<<dim3(32, 64), 256, 0, stream>>>(o_proj_w, 1024, 0, owt, 2048);

  // conv as GEMM (K=3072 overlapping-row trick, lda=1024)
  gemm_t<0, 128, 64><<<dim3(16, 32), 256, 0, stream>>>(xb, 1024, cwt, 3072, 3072, conv_b, xc, 2048, xcb, nullptr);
  // z projection
  gemm_t<1, 128, 64><<<dim3(16, 32), 256, 0, stream>>>(xb + 2 * 1024, 1024, wzt, 1024, 1024, in_proj_b + 2048, zpre, 2048, nullptr, nullptr);
  bcdt<<<2048, 256, 0, stream>>>(xc, x_proj_w, x_proj_b, Bc, Cc, dtv);
  // gate: u = xc * sigmoid(xcb @ gwt^T + gate_b)
  gemm_t<2, 128, 64><<<dim3(16, 32), 256, 0, stream>>>(xcb, 2048, gwt, 2048, 2048, gate_b, uu, 2048, nullptr, xc);

  scan_local<<<dim3(8, NCH), 256, 0, stream>>>(A_log, dtv, Bc, uu, Hloc);
  scan_carry<<<128, 256, 0, stream>>>(A_log, dtv, Hloc, hstart);
  scan_final<<<dim3(8, NCH), 256, 0, stream>>>(A_log, dtv, Bc, Cc, uu, zpre, Dp, hstart, ob);

  // output projection (64x64 tiles -> 512 blocks, 2/CU)
  gemm_t<1, 64, 64><<<dim3(32, 16), 256, 0, stream>>>(ob, 2048, owt, 2048, 2048, o_proj_b, (float*)d_out, 1024, nullptr, nullptr);
}